// Round 5
// baseline (135.323 us; speedup 1.0000x reference)
//
#include <hip/hip_runtime.h>
#include <math.h>

#define NE 8
#define NT 512
#define NH 1024
#define NF 2816
#define NG 128
#define TWO_F (2*NF)      // 5632
#define HP (NH/8)         // 128 packed rows for w13
#define FP (NF/8)         // 352 packed rows for w2
#define H_GROUPS (NH/NG)  // 8
#define F_GROUPS (NF/NG)  // 22
#define INV254 (1.0f/254.0f)

typedef __attribute__((ext_vector_type(4))) int   int4v;
typedef __attribute__((ext_vector_type(4))) float f32x4;
typedef __attribute__((ext_vector_type(8))) short short8;

__device__ inline short f2bf(float f) {
    unsigned u = __float_as_uint(f);
    u += 0x7FFFu + ((u >> 16) & 1u);   // RNE
    return (short)(u >> 16);
}
__device__ inline float bf2f(short s) {
    return __uint_as_float(((unsigned)(unsigned short)s) << 16);
}

// 16 nibbles (2 packed ints, k-order) -> 16 int8 bytes = (nib - 8)
__device__ inline int4v unpack16(int q0, int q1) {
    int e0 = q0 & 0x0F0F0F0F, o0 = ((unsigned)q0 >> 4) & 0x0F0F0F0F;
    int e1 = q1 & 0x0F0F0F0F, o1 = ((unsigned)q1 >> 4) & 0x0F0F0F0F;
    int4v b;
    b[0] = (__builtin_amdgcn_perm(o0, e0, 0x05010400) + 0x78787878) ^ 0x80808080;
    b[1] = (__builtin_amdgcn_perm(o0, e0, 0x07030602) + 0x78787878) ^ 0x80808080;
    b[2] = (__builtin_amdgcn_perm(o1, e1, 0x05010400) + 0x78787878) ^ 0x80808080;
    b[3] = (__builtin_amdgcn_perm(o1, e1, 0x07030602) + 0x78787878) ^ 0x80808080;
    return b;
}

__device__ inline int pack4(const int* b) {
    return (b[0] & 255) | ((b[1] & 255) << 8) | ((b[2] & 255) << 16) | ((b[3] & 255) << 24);
}

// -------- fused routing (softmax->top2->renorm) + stable expert binning ----
__global__ __launch_bounds__(512) void route_bin_kernel(
        const float* __restrict__ logits,
        float* __restrict__ topk_w,
        int* __restrict__ counts,
        int* __restrict__ tok_list) {
    __shared__ int sh_e[2 * NT];
    const int t = threadIdx.x;   // one token per thread, NT==512
    float l[NE];
#pragma unroll
    for (int e = 0; e < NE; ++e) l[e] = logits[t * NE + e];
    int i0 = 0; float v0 = l[0];
#pragma unroll
    for (int e = 1; e < NE; ++e) { if (l[e] > v0) { v0 = l[e]; i0 = e; } }
    int i1 = -1; float v1 = -INFINITY;
#pragma unroll
    for (int e = 0; e < NE; ++e) {
        if (e == i0) continue;
        if (l[e] > v1) { v1 = l[e]; i1 = e; }
    }
    float e1 = expf(v1 - v0);
    float inv = 1.0f / (1.0f + e1);
    topk_w[t * 2 + 0] = inv;
    topk_w[t * 2 + 1] = e1 * inv;
    sh_e[t * 2 + 0] = i0;
    sh_e[t * 2 + 1] = i1;
    __syncthreads();
    const int w = t >> 6, lane = t & 63;
    int base = 0;
    for (int chunk = 0; chunk < 16; ++chunk) {
        int j = chunk * 64 + lane;
        bool m = (sh_e[j] == w);
        unsigned long long mask = __ballot(m);
        if (m) {
            int pos = base + __popcll(mask & ((1ull << lane) - 1ull));
            tok_list[w * NT + pos] = j;   // j = t*2 + slot
        }
        base += __popcll(mask);
    }
    if (lane == 0) counts[w] = base;
}

// -------- x -> dual int8 (hi + lo/254), per-row scale --------
__global__ __launch_bounds__(256) void quant_x_kernel(const float* __restrict__ x,
                                                      char* __restrict__ xh,
                                                      char* __restrict__ xl,
                                                      float* __restrict__ sx) {
    __shared__ float wmax[4];
    const int t = blockIdx.x;
    const int tid = threadIdx.x;
    f32x4 v = *(const f32x4*)(x + (size_t)t * NH + tid * 4);
    float m = fmaxf(fmaxf(fabsf(v[0]), fabsf(v[1])), fmaxf(fabsf(v[2]), fabsf(v[3])));
#pragma unroll
    for (int off = 32; off >= 1; off >>= 1)
        m = fmaxf(m, __shfl_xor(m, off, 64));
    if ((tid & 63) == 0) wmax[tid >> 6] = m;
    __syncthreads();
    float amax = fmaxf(fmaxf(wmax[0], wmax[1]), fmaxf(wmax[2], wmax[3]));
    float scale = (amax > 0.f) ? amax / 127.f : 0.f;
    float invs  = (amax > 0.f) ? 127.f / amax : 0.f;
    if (tid == 0) sx[t] = scale;
    int bh[4], bl[4];
#pragma unroll
    for (int j = 0; j < 4; ++j) {
        float xs = v[j] * invs;                     // in [-127,127]
        float qh = rintf(xs);
        qh = fminf(fmaxf(qh, -127.f), 127.f);
        float ql = rintf((xs - qh) * 254.f);        // in [-127,127]
        ql = fminf(fmaxf(ql, -127.f), 127.f);
        bh[j] = (int)qh; bl[j] = (int)ql;
    }
    ((int*)xh)[t * (NH / 4) + tid] = pack4(bh);
    ((int*)xl)[t * (NH / 4) + tid] = pack4(bl);
}

// ------- GEMM1 + silu fused (dual int8 MFMA): a = silu(x@Wg)*(x@Wu) --------
// block tile: 64 M x 32 F, 4 waves = (mh, fh); wave: 32 M x 16 F (g and u)
__global__ __launch_bounds__(256) void gemm1_act_kernel(
        const char*  __restrict__ xh,
        const char*  __restrict__ xl,
        const float* __restrict__ sx,
        const int*   __restrict__ w13q,
        const float* __restrict__ s13,
        const int*   __restrict__ counts,
        const int*   __restrict__ tok_list,
        short* __restrict__ a_ws) {
    const int e = blockIdx.z;
    const int me = counts[e];
    const int mtile = blockIdx.y;
    if (mtile * 64 >= me) return;
    const int ntile = blockIdx.x;          // 0..87, 32 F each
    const int tid = threadIdx.x;
    const int w = tid >> 6, l = tid & 63;
    const int lr = l & 15, kg = l >> 4;
    const int mh = w >> 1, fh = w & 1;
    const int rb = mtile * 64 + mh * 32;
    const int cF = ntile * 32 + fh * 16;   // g col = cF+lr, u col = NF+cF+lr
    const int* tl = tok_list + e * NT;

    const char* xAh[2]; const char* xAl[2];
#pragma unroll
    for (int ms = 0; ms < 2; ++ms) {
        int i = rb + ms * 16 + lr;
        if (i >= me) i = me - 1;
        const size_t off = (size_t)(tl[i] >> 1) * NH;
        xAh[ms] = xh + off;
        xAl[ms] = xl + off;
    }

    f32x4 fg[2], fu[2];
#pragma unroll
    for (int ms = 0; ms < 2; ++ms) { fg[ms] = (f32x4)0.f; fu[ms] = (f32x4)0.f; }

    for (int kb = 0; kb < H_GROUPS; ++kb) {
        const float scg  = s13[(size_t)(e * H_GROUPS + kb) * TWO_F + cF + lr];
        const float scu  = s13[(size_t)(e * H_GROUPS + kb) * TWO_F + NF + cF + lr];
        const float scg2 = scg * INV254;
        const float scu2 = scu * INV254;
        int4v ihg[2], ilg[2], ihu[2], ilu[2];
#pragma unroll
        for (int ms = 0; ms < 2; ++ms) { ihg[ms] = (int4v)0; ilg[ms] = (int4v)0; ihu[ms] = (int4v)0; ilu[ms] = (int4v)0; }
#pragma unroll
        for (int ks = 0; ks < 2; ++ks) {
            const int k0 = kb * 128 + ks * 64;
            int4v ah[2], al[2];
#pragma unroll
            for (int ms = 0; ms < 2; ++ms) {
                ah[ms] = *(const int4v*)(xAh[ms] + k0 + kg * 16);
                al[ms] = *(const int4v*)(xAl[ms] + k0 + kg * 16);
            }
            const int kp = (k0 >> 3) + kg * 2;
            const int* bq = w13q + ((size_t)e * HP + kp) * TWO_F;
            const int qg0 = bq[cF + lr],      qg1 = bq[TWO_F + cF + lr];
            const int qu0 = bq[NF + cF + lr], qu1 = bq[TWO_F + NF + cF + lr];
            const int4v bg = unpack16(qg0, qg1);
            const int4v bu = unpack16(qu0, qu1);
#pragma unroll
            for (int ms = 0; ms < 2; ++ms) {
                ihg[ms] = __builtin_amdgcn_mfma_i32_16x16x64_i8(ah[ms], bg, ihg[ms], 0, 0, 0);
                ilg[ms] = __builtin_amdgcn_mfma_i32_16x16x64_i8(al[ms], bg, ilg[ms], 0, 0, 0);
                ihu[ms] = __builtin_amdgcn_mfma_i32_16x16x64_i8(ah[ms], bu, ihu[ms], 0, 0, 0);
                ilu[ms] = __builtin_amdgcn_mfma_i32_16x16x64_i8(al[ms], bu, ilu[ms], 0, 0, 0);
            }
        }
#pragma unroll
        for (int ms = 0; ms < 2; ++ms)
#pragma unroll
            for (int r = 0; r < 4; ++r) {
                fg[ms][r] += scg * (float)ihg[ms][r] + scg2 * (float)ilg[ms][r];
                fu[ms][r] += scu * (float)ihu[ms][r] + scu2 * (float)ilu[ms][r];
            }
    }
    // epilogue: C row = kg*4 + r (+ms*16), col = lr; h = sx[m] * facc
#pragma unroll
    for (int ms = 0; ms < 2; ++ms) {
#pragma unroll
        for (int r = 0; r < 4; ++r) {
            const int orow = rb + ms * 16 + kg * 4 + r;
            if (orow < me) {
                const int t2s = tl[orow];
                const float sxm = sx[t2s >> 1];
                const float g = sxm * fg[ms][r];
                const float u = sxm * fu[ms][r];
                const float aval = (g / (1.0f + __expf(-g))) * u;
                a_ws[(size_t)t2s * NF + cF + lr] = f2bf(aval);
            }
        }
    }
}

// -------- a (bf16) -> dual int8, per-row scale --------
__global__ __launch_bounds__(256) void quant_a_kernel(const short* __restrict__ a_ws,
                                                      char* __restrict__ ah,
                                                      char* __restrict__ al,
                                                      float* __restrict__ sxa) {
    __shared__ float wmax[4];
    const int row = blockIdx.x;            // t2s in [0, 1024)
    const int tid = threadIdx.x;
    const short* src = a_ws + (size_t)row * NF;
    float m = 0.f;
    short8 v[2];
#pragma unroll
    for (int it = 0; it < 2; ++it) {
        const int i = tid + it * 256;
        if (i < NF / 8) {
            v[it] = *(const short8*)(src + i * 8);
#pragma unroll
            for (int j = 0; j < 8; ++j) m = fmaxf(m, fabsf(bf2f(v[it][j])));
        }
    }
#pragma unroll
    for (int off = 32; off >= 1; off >>= 1)
        m = fmaxf(m, __shfl_xor(m, off, 64));
    if ((tid & 63) == 0) wmax[tid >> 6] = m;
    __syncthreads();
    float amax = fmaxf(fmaxf(wmax[0], wmax[1]), fmaxf(wmax[2], wmax[3]));
    float scale = (amax > 0.f) ? amax / 127.f : 0.f;
    float invs  = (amax > 0.f) ? 127.f / amax : 0.f;
    if (tid == 0) sxa[row] = scale;
#pragma unroll
    for (int it = 0; it < 2; ++it) {
        const int i = tid + it * 256;
        if (i < NF / 8) {
            int dh[2], dl[2];
#pragma unroll
            for (int h = 0; h < 2; ++h) {
                int bh[4], bl[4];
#pragma unroll
                for (int j = 0; j < 4; ++j) {
                    float xs = bf2f(v[it][h * 4 + j]) * invs;
                    float qh = rintf(xs);
                    qh = fminf(fmaxf(qh, -127.f), 127.f);
                    float ql = rintf((xs - qh) * 254.f);
                    ql = fminf(fmaxf(ql, -127.f), 127.f);
                    bh[j] = (int)qh; bl[j] = (int)ql;
                }
                dh[h] = pack4(bh); dl[h] = pack4(bl);
            }
            *(int2*)(ah + (size_t)row * NF + i * 8) = make_int2(dh[0], dh[1]);
            *(int2*)(al + (size_t)row * NF + i * 8) = make_int2(dl[0], dl[1]);
        }
    }
}

// ------- GEMM2 (dual int8): out += wgt*sxa*(A_e @ W2_e), wave K-split(4) ----
// block tile 64M x 32N; 4 waves over interleaved K-groups; LDS reduce.
__global__ __launch_bounds__(256) void gemm2_kernel(
        const char*  __restrict__ ahq,
        const char*  __restrict__ alq,
        const float* __restrict__ sxa,
        const int*   __restrict__ w2q,
        const float* __restrict__ s2,
        const int*   __restrict__ counts,
        const int*   __restrict__ tok_list,
        const float* __restrict__ topk_w,
        float* __restrict__ out) {
    __shared__ float red[3][64][33];
    const int e = blockIdx.z;
    const int me = counts[e];
    const int mtile = blockIdx.y;
    if (mtile * 64 >= me) return;
    const int ntile = blockIdx.x;          // 0..31
    const int tid = threadIdx.x;
    const int kh = tid >> 6, l = tid & 63;
    const int lr = l & 15, kg = l >> 4;
    const int rb = mtile * 64;
    const int cb = ntile * 32;
    const int* tl = tok_list + e * NT;

    const char* aAh[4]; const char* aAl[4];
#pragma unroll
    for (int ms = 0; ms < 4; ++ms) {
        int i = rb + ms * 16 + lr;
        if (i >= me) i = me - 1;
        const size_t off = (size_t)tl[i] * NF;
        aAh[ms] = ahq + off;
        aAl[ms] = alq + off;
    }

    f32x4 facc[4][2];
#pragma unroll
    for (int ms = 0; ms < 4; ++ms)
#pragma unroll
        for (int ns = 0; ns < 2; ++ns) facc[ms][ns] = (f32x4)0.f;

    for (int g = kh; g < F_GROUPS; g += 4) {
        float sc[2], sc2[2];
#pragma unroll
        for (int ns = 0; ns < 2; ++ns) {
            sc[ns] = s2[(size_t)(e * F_GROUPS + g) * NH + cb + ns * 16 + lr];
            sc2[ns] = sc[ns] * INV254;
        }
        int4v ih[4][2], il[4][2];
#pragma unroll
        for (int ms = 0; ms < 4; ++ms)
#pragma unroll
            for (int ns = 0; ns < 2; ++ns) { ih[ms][ns] = (int4v)0; il[ms][ns] = (int4v)0; }
#pragma unroll
        for (int ks = 0; ks < 2; ++ks) {
            const int k0 = g * 128 + ks * 64;
            int4v a_h[4], a_l[4];
#pragma unroll
            for (int ms = 0; ms < 4; ++ms) {
                a_h[ms] = *(const int4v*)(aAh[ms] + k0 + kg * 16);
                a_l[ms] = *(const int4v*)(aAl[ms] + k0 + kg * 16);
            }
            const int kp = (k0 >> 3) + kg * 2;
            const int* bq = w2q + ((size_t)e * FP + kp) * NH;
            int q0[2], q1[2];
#pragma unroll
            for (int ns = 0; ns < 2; ++ns) {
                q0[ns] = bq[cb + ns * 16 + lr];
                q1[ns] = bq[NH + cb + ns * 16 + lr];
            }
#pragma unroll
            for (int ns = 0; ns < 2; ++ns) {
                const int4v b = unpack16(q0[ns], q1[ns]);
#pragma unroll
                for (int ms = 0; ms < 4; ++ms) {
                    ih[ms][ns] = __builtin_amdgcn_mfma_i32_16x16x64_i8(a_h[ms], b, ih[ms][ns], 0, 0, 0);
                    il[ms][ns] = __builtin_amdgcn_mfma_i32_16x16x64_i8(a_l[ms], b, il[ms][ns], 0, 0, 0);
                }
            }
        }
#pragma unroll
        for (int ms = 0; ms < 4; ++ms)
#pragma unroll
            for (int ns = 0; ns < 2; ++ns)
#pragma unroll
                for (int r = 0; r < 4; ++r)
                    facc[ms][ns][r] += sc[ns] * (float)ih[ms][ns][r] + sc2[ns] * (float)il[ms][ns][r];
    }

    if (kh > 0) {
#pragma unroll
        for (int ms = 0; ms < 4; ++ms)
#pragma unroll
            for (int ns = 0; ns < 2; ++ns)
#pragma unroll
                for (int r = 0; r < 4; ++r)
                    red[kh - 1][ms * 16 + kg * 4 + r][ns * 16 + lr] = facc[ms][ns][r];
    }
    __syncthreads();
    if (kh == 0) {
#pragma unroll
        for (int ms = 0; ms < 4; ++ms) {
#pragma unroll
            for (int r = 0; r < 4; ++r) {
                const int rowLoc = ms * 16 + kg * 4 + r;
                const int orow = rb + rowLoc;
                if (orow < me) {
                    const int t2s = tl[orow];
                    const float wscale = topk_w[t2s] * sxa[t2s];
#pragma unroll
                    for (int ns = 0; ns < 2; ++ns) {
                        float v = facc[ms][ns][r]
                                + red[0][rowLoc][ns * 16 + lr]
                                + red[1][rowLoc][ns * 16 + lr]
                                + red[2][rowLoc][ns * 16 + lr];
                        // exactly 2 atomic adds per out element -> deterministic
                        atomicAdd(out + (size_t)(t2s >> 1) * NH + cb + ns * 16 + lr, wscale * v);
                    }
                }
            }
        }
    }
}

extern "C" void kernel_launch(void* const* d_in, const int* in_sizes, int n_in,
                              void* d_out, int out_size, void* d_ws, size_t ws_size,
                              hipStream_t stream) {
    const float* x      = (const float*)d_in[0];
    const float* logits = (const float*)d_in[1];
    const int*   w13q   = (const int*)d_in[2];
    const int*   w2q    = (const int*)d_in[3];
    const float* s13    = (const float*)d_in[4];
    const float* s2     = (const float*)d_in[5];

    char* ws = (char*)d_ws;
    size_t o = 0;
    int*   counts   = (int*)(ws + o);   o += 4096;
    float* topk_w   = (float*)(ws + o); o += 4096;
    int*   tok_list = (int*)(ws + o);   o += 16384;
    float* sx       = (float*)(ws + o); o += 4096;
    float* sxa      = (float*)(ws + o); o += 4096;
    char*  xh       = ws + o;           o += (size_t)NT * NH;          // 512 KB
    char*  xl       = ws + o;           o += (size_t)NT * NH;          // 512 KB
    short* a_ws     = (short*)(ws + o); o += (size_t)2 * NT * NF * 2;  // 5.77 MB
    char*  ahq      = ws + o;           o += (size_t)2 * NT * NF;      // 2.88 MB
    char*  alq      = ws + o;           o += (size_t)2 * NT * NF;      // 2.88 MB

    hipMemsetAsync(d_out, 0, (size_t)out_size * sizeof(float), stream);
    route_bin_kernel<<<1, 512, 0, stream>>>(logits, topk_w, counts, tok_list);
    quant_x_kernel<<<NT, 256, 0, stream>>>(x, xh, xl, sx);
    gemm1_act_kernel<<<dim3(NF / 32, 8, NE), 256, 0, stream>>>(
        xh, xl, sx, w13q, s13, counts, tok_list, a_ws);
    quant_a_kernel<<<2 * NT, 256, 0, stream>>>(a_ws, ahq, alq, sxa);
    gemm2_kernel<<<dim3(NH / 32, 8, NE), 256, 0, stream>>>(
        ahq, alq, sxa, w2q, s2, counts, tok_list, topk_w, (float*)d_out);
}